// Round 1
// baseline (594.403 us; speedup 1.0000x reference)
//
#include <hip/hip_runtime.h>
#include <hip/hip_cooperative_groups.h>
#include <math.h>

// BandpassFilter: out = lowpass_biquad(x) - highpass_biquad(x), f32,
// shape (32,2,220500). Exact chunked-scan parallelization of the order-2 IIR.
//
// R3: single cooperative kernel. R2 counters showed neither pass is BW-bound
// (2.8 TB/s combined, VALUBusy 10%) — the cost was structural: x read from
// HBM twice (112 of 183 MB traffic), plus a 32-block latency-bound scan
// dispatch idling the device. Now each thread keeps its 64-sample chunk in
// registers (statically indexed -> VGPRs), computes tails, grid.sync()s,
// 32 blocks run the wave-scan in-place, grid.sync()s, and the exact pass
// reruns from registers. x is fetched once; scan costs ~µs not a dispatch.
// Fallback to the proven 3-kernel path if cooperative launch is refused.

namespace cg = cooperative_groups;

namespace {

constexpr int T_LEN  = 220500;
constexpr int NCH    = 64;                          // 32 batch * 2 channels
constexpr int CHUNK  = 64;                          // samples per chunk
constexpr int NCHUNK = (T_LEN + CHUNK - 1) / CHUNK; // 3446 (last chunk = 20)
constexpr int NPAIR  = NCH * 2;                     // (channel, filter) pairs
constexpr int RUN    = (NCHUNK + 63) / 64;          // 54 chunk-elems per lane in scan
constexpr int CPB    = 256;                         // chunks per block
constexpr int BX     = (NCHUNK + CPB - 1) / CPB;    // 14 blocks along chunk dim
constexpr int HALF   = 32;                          // samples staged per tile
constexpr int LSTR   = HALF + 1;                    // 33: pad-1 -> conflict-free
constexpr int SCAN_BLOCKS = NPAIR / 4;              // 32 blocks x 4 waves = 128 waves

struct Coeffs { float b0, b1, b2, a1, a2; };

__device__ inline Coeffs make_coeffs(float sr, float cutoff, bool hp) {
    float w0 = 6.2831853071795864f * cutoff / sr;
    float c = cosf(w0), s = sinf(w0);
    float alpha = s / (2.0f * 0.707f);
    float b0, b1;
    if (!hp) { b0 = (1.0f - c) * 0.5f; b1 = 1.0f - c; }
    else     { b0 = (1.0f + c) * 0.5f; b1 = -(1.0f + c); }
    float inv = 1.0f / (1.0f + alpha);
    Coeffs k;
    k.b0 = b0 * inv; k.b1 = b1 * inv; k.b2 = b0 * inv;
    k.a1 = (-2.0f * c) * inv;
    k.a2 = (1.0f - alpha) * inv;
    return k;
}

// one sample through both filters; returns yl - yh
__device__ inline float proc_sample(float xn, float& x1, float& x2,
                                    const Coeffs& lo, const Coeffs& hi,
                                    float& yl1, float& yl2,
                                    float& yh1, float& yh2) {
    float ffl = fmaf(lo.b0, xn, fmaf(lo.b1, x1, lo.b2 * x2));
    float tl  = fmaf(-lo.a2, yl2, ffl);
    float yl  = fmaf(-lo.a1, yl1, tl);
    float ffh = fmaf(hi.b0, xn, fmaf(hi.b1, x1, hi.b2 * x2));
    float th  = fmaf(-hi.a2, yh2, ffh);
    float yh  = fmaf(-hi.a1, yh1, th);
    yl2 = yl1; yl1 = yl;
    yh2 = yh1; yh1 = yh;
    x2 = x1; x1 = xn;
    return yl - yh;
}

// Wave-level affine scan over one (channel, filter) pair's chunk tails.
// gw in [0, NPAIR), lane in [0, 64). Identical math to the standalone k_scan.
__device__ inline void scan_pair(int gw, int lane, float sr,
                                 const float* __restrict__ clp,
                                 const float* __restrict__ chp,
                                 const float2* __restrict__ tails,
                                 float2* __restrict__ inits) {
    int f = gw & 1;
    Coeffs k = make_coeffs(sr, f ? (*chp) : (*clp), f != 0);

    // M^CHUNK via 6 squarings (CHUNK = 64)
    float m00 = -k.a1, m01 = -k.a2, m10 = 1.0f, m11 = 0.0f;
    #pragma unroll
    for (int i = 0; i < 6; ++i) {
        float t00 = fmaf(m00, m00, m01 * m10);
        float t01 = fmaf(m00, m01, m01 * m11);
        float t10 = fmaf(m10, m00, m11 * m10);
        float t11 = fmaf(m10, m01, m11 * m11);
        m00 = t00; m01 = t01; m10 = t10; m11 = t11;
    }

    const float2* __restrict__ tp = tails + (size_t)gw * NCHUNK;
    float2* __restrict__ ip = inits + (size_t)gw * NCHUNK;

    int s0 = lane * RUN;
    int s1 = min(s0 + RUN, NCHUNK);

    float A00 = 1.f, A01 = 0.f, A10 = 0.f, A11 = 1.f, c0 = 0.f, c1 = 0.f;
    for (int p = s0; p < s1; ++p) {
        float2 t = tp[p];
        float nA00 = fmaf(m00, A00, m01 * A10);
        float nA01 = fmaf(m00, A01, m01 * A11);
        float nA10 = fmaf(m10, A00, m11 * A10);
        float nA11 = fmaf(m10, A01, m11 * A11);
        float nc0  = fmaf(m00, c0, fmaf(m01, c1, t.x));
        float nc1  = fmaf(m10, c0, fmaf(m11, c1, t.y));
        A00 = nA00; A01 = nA01; A10 = nA10; A11 = nA11; c0 = nc0; c1 = nc1;
    }

    #pragma unroll
    for (int d = 1; d < 64; d <<= 1) {
        float pA00 = __shfl_up(A00, d);
        float pA01 = __shfl_up(A01, d);
        float pA10 = __shfl_up(A10, d);
        float pA11 = __shfl_up(A11, d);
        float pc0  = __shfl_up(c0, d);
        float pc1  = __shfl_up(c1, d);
        if (lane >= d) {
            float nA00 = fmaf(A00, pA00, A01 * pA10);
            float nA01 = fmaf(A00, pA01, A01 * pA11);
            float nA10 = fmaf(A10, pA00, A11 * pA10);
            float nA11 = fmaf(A10, pA01, A11 * pA11);
            float nc0  = fmaf(A00, pc0, fmaf(A01, pc1, c0));
            float nc1  = fmaf(A10, pc0, fmaf(A11, pc1, c1));
            A00 = nA00; A01 = nA01; A10 = nA10; A11 = nA11; c0 = nc0; c1 = nc1;
        }
    }
    float e0 = __shfl_up(c0, 1);
    float e1 = __shfl_up(c1, 1);
    if (lane == 0) { e0 = 0.0f; e1 = 0.0f; }

    float sA = e0, sB = e1;
    for (int p = s0; p < s1; ++p) {
        ip[p] = make_float2(sA, sB);
        float2 t = tp[p];
        float n0 = fmaf(m00, sA, fmaf(m01, sB, t.x));
        float n1 = fmaf(m10, sA, fmaf(m11, sB, t.y));
        sA = n0; sB = n1;
    }
}

// ---------------------------------------------------------------------------
// Fused cooperative kernel: load x once into registers, tails pass,
// grid-sync, in-kernel scan, grid-sync, exact pass + store.
// __launch_bounds__(256,4): VGPR<=128 -> with LDS 33792B -> 4 blocks/CU ->
// co-residency capacity 1024 blocks >= 896 launched.
// ---------------------------------------------------------------------------
__global__ __launch_bounds__(256, 4)
void k_fused(const float* __restrict__ x,
             const int* __restrict__ srp,
             const float* __restrict__ clp,
             const float* __restrict__ chp,
             float2* __restrict__ tails,
             float2* __restrict__ inits,
             float* __restrict__ out) {
    __shared__ float lds[CPB * LSTR];   // 33,792 B
    cg::grid_group grid = cg::this_grid();

    const int t   = threadIdx.x;
    const int ch  = blockIdx.y;
    const int bx  = blockIdx.x;
    const int pb  = bx * CPB;
    const int p   = pb + t;
    const int bid = ch * BX + bx;       // flat block id, 0..895

    float sr = (float)(*srp);
    Coeffs lo = make_coeffs(sr, *clp, false);
    Coeffs hi = make_coeffs(sr, *chp, true);

    const float* __restrict__ xc = x + (size_t)ch * T_LEN;
    const bool active = (p < NCHUNK);
    const int s = p * CHUNK;
    const int regBase = pb * CHUNK;

    // Per-thread chunk in registers. All indexing below is compile-time
    // constant (full unrolls) -> stays in VGPRs, never scratch.
    float xr[CHUNK];

    // ---- load x once: two LDS-transposed halves (coalesced float4 reads).
    // OOB region zero-filled so the full-64 unrolled passes below are safe
    // (the only partial chunk is the last; its tail is never consumed and
    // its OOB outputs are never stored).
    #pragma unroll
    for (int h = 0; h < 2; ++h) {
        #pragma unroll
        for (int i = 0; i < (CPB * HALF) / (4 * 256); ++i) {   // 8 iters
            int f4 = i * 256 + t;
            int c  = f4 >> 3;
            int j0 = (f4 & 7) * 4;
            int g  = regBase + c * CHUNK + h * HALF + j0;
            float4 v = make_float4(0.f, 0.f, 0.f, 0.f);
            if (g < T_LEN) v = *(const float4*)(xc + g);   // T_LEN%4==0
            float* d = &lds[c * LSTR + j0];
            d[0] = v.x; d[1] = v.y; d[2] = v.z; d[3] = v.w;
        }
        __syncthreads();
        {
            const float* __restrict__ L = &lds[t * LSTR];
            #pragma unroll
            for (int j = 0; j < HALF; ++j) xr[h * HALF + j] = L[j];
        }
        __syncthreads();
    }

    // x history (2 scalar loads; lines L2-hot from staging)
    float x1 = (active && s >= 1) ? xc[s - 1] : 0.0f;
    float x2 = (active && s >= 2) ? xc[s - 2] : 0.0f;

    // ---- phase A: zero-state run over registers, record 2-tap tails
    {
        float ax1 = x1, ax2 = x2;
        float yl1 = 0.f, yl2 = 0.f, yh1 = 0.f, yh2 = 0.f;
        #pragma unroll
        for (int j = 0; j < CHUNK; ++j)
            (void)proc_sample(xr[j], ax1, ax2, lo, hi, yl1, yl2, yh1, yh2);
        if (active) {
            tails[(size_t)(ch * 2 + 0) * NCHUNK + p] = make_float2(yl1, yl2);
            tails[(size_t)(ch * 2 + 1) * NCHUNK + p] = make_float2(yh1, yh2);
        }
    }
    __threadfence();      // make tails visible device-wide (cross-XCD)
    grid.sync();

    // ---- phase B: 128 scan waves (first 32 blocks); everyone else waits
    if (bid < SCAN_BLOCKS) {
        int gw   = bid * 4 + (t >> 6);   // 0..127
        int lane = t & 63;
        scan_pair(gw, lane, sr, clp, chp, tails, inits);
        __threadfence();  // make inits visible device-wide
    }
    grid.sync();

    // ---- phase C: exact run from registers with scanned init states
    float yl1 = 0.f, yl2 = 0.f, yh1 = 0.f, yh2 = 0.f;
    if (active) {
        float2 il = inits[(size_t)(ch * 2 + 0) * NCHUNK + p];
        float2 ih = inits[(size_t)(ch * 2 + 1) * NCHUNK + p];
        yl1 = il.x; yl2 = il.y; yh1 = ih.x; yh2 = ih.y;
    }
    float* __restrict__ oc = out + (size_t)ch * T_LEN;

    #pragma unroll
    for (int h = 0; h < 2; ++h) {
        {
            float* __restrict__ L = &lds[t * LSTR];
            #pragma unroll
            for (int j = 0; j < HALF; ++j)
                L[j] = proc_sample(xr[h * HALF + j], x1, x2, lo, hi,
                                   yl1, yl2, yh1, yh2);
        }
        __syncthreads();
        #pragma unroll
        for (int i = 0; i < (CPB * HALF) / (4 * 256); ++i) {
            int f4 = i * 256 + t;
            int c  = f4 >> 3;
            int j0 = (f4 & 7) * 4;
            int g  = regBase + c * CHUNK + h * HALF + j0;
            if (g < T_LEN) {
                const float* sld = &lds[c * LSTR + j0];
                *(float4*)(oc + g) = make_float4(sld[0], sld[1], sld[2], sld[3]);
            }
        }
        __syncthreads();
    }
}

// ---------------------------------------------------------------------------
// Fallback path (R2's proven 3-kernel pipeline) — used only if the
// cooperative launch is refused by the runtime.
// ---------------------------------------------------------------------------
template <bool FINAL>
__global__ __launch_bounds__(256)
void k_pass(const float* __restrict__ x,
            const int* __restrict__ srp,
            const float* __restrict__ clp,
            const float* __restrict__ chp,
            float2* __restrict__ tails,
            const float2* __restrict__ inits,
            float* __restrict__ out) {
    __shared__ float lds[CPB * LSTR];

    const int t  = threadIdx.x;
    const int ch = blockIdx.y;
    const int pb = blockIdx.x * CPB;
    const int p  = pb + t;

    float sr = (float)(*srp);
    Coeffs lo = make_coeffs(sr, *clp, false);
    Coeffs hi = make_coeffs(sr, *chp, true);

    const float* __restrict__ xc = x + (size_t)ch * T_LEN;
    float* __restrict__ oc = out + (size_t)ch * T_LEN;

    const bool active = (p < NCHUNK);
    const int s   = p * CHUNK;
    const int len = active ? min(CHUNK, T_LEN - s) : 0;

    float x1 = (active && s >= 1) ? xc[s - 1] : 0.0f;
    float x2 = (active && s >= 2) ? xc[s - 2] : 0.0f;
    float yl1 = 0.0f, yl2 = 0.0f, yh1 = 0.0f, yh2 = 0.0f;
    if (FINAL && active) {
        float2 il = inits[(size_t)(ch * 2 + 0) * NCHUNK + p];
        float2 ih = inits[(size_t)(ch * 2 + 1) * NCHUNK + p];
        yl1 = il.x; yl2 = il.y; yh1 = ih.x; yh2 = ih.y;
    }

    const int regBase = pb * CHUNK;

    #pragma unroll
    for (int h = 0; h < 2; ++h) {
        #pragma unroll
        for (int i = 0; i < (CPB * HALF) / (4 * 256); ++i) {
            int f4 = i * 256 + t;
            int c  = f4 >> 3;
            int j0 = (f4 & 7) * 4;
            int g  = regBase + c * CHUNK + h * HALF + j0;
            if (g < T_LEN) {
                float4 v = *(const float4*)(xc + g);
                float* d = &lds[c * LSTR + j0];
                d[0] = v.x; d[1] = v.y; d[2] = v.z; d[3] = v.w;
            }
        }
        __syncthreads();

        {
            int n = len - h * HALF;
            if (n > HALF) n = HALF;
            float* __restrict__ L = &lds[t * LSTR];
            if (n == HALF) {
                #pragma unroll
                for (int j = 0; j < HALF; ++j) {
                    float y = proc_sample(L[j], x1, x2, lo, hi, yl1, yl2, yh1, yh2);
                    if (FINAL) L[j] = y;
                }
            } else {
                for (int j = 0; j < n; ++j) {
                    float y = proc_sample(L[j], x1, x2, lo, hi, yl1, yl2, yh1, yh2);
                    if (FINAL) L[j] = y;
                }
            }
        }
        __syncthreads();

        if (FINAL) {
            #pragma unroll
            for (int i = 0; i < (CPB * HALF) / (4 * 256); ++i) {
                int f4 = i * 256 + t;
                int c  = f4 >> 3;
                int j0 = (f4 & 7) * 4;
                int g  = regBase + c * CHUNK + h * HALF + j0;
                if (g < T_LEN) {
                    const float* sld = &lds[c * LSTR + j0];
                    float4 v = make_float4(sld[0], sld[1], sld[2], sld[3]);
                    *(float4*)(oc + g) = v;
                }
            }
            __syncthreads();
        }
    }

    if (!FINAL && active) {
        tails[(size_t)(ch * 2 + 0) * NCHUNK + p] = make_float2(yl1, yl2);
        tails[(size_t)(ch * 2 + 1) * NCHUNK + p] = make_float2(yh1, yh2);
    }
}

__global__ __launch_bounds__(256)
void k_scan(const int* __restrict__ srp,
            const float* __restrict__ clp,
            const float* __restrict__ chp,
            const float2* __restrict__ tails,
            float2* __restrict__ inits) {
    int gtid = blockIdx.x * 256 + threadIdx.x;
    int wid  = gtid >> 6;
    int lane = threadIdx.x & 63;
    float sr = (float)(*srp);
    scan_pair(wid, lane, sr, clp, chp, tails, inits);
}

} // namespace

extern "C" void kernel_launch(void* const* d_in, const int* in_sizes, int n_in,
                              void* d_out, int out_size, void* d_ws, size_t ws_size,
                              hipStream_t stream) {
    const float* audio = (const float*)d_in[0];
    const int*   srp   = (const int*)d_in[1];
    const float* clp   = (const float*)d_in[2];
    const float* chp   = (const float*)d_in[3];
    float* out = (float*)d_out;

    float2* tails = (float2*)d_ws;                        // [NPAIR][NCHUNK]
    float2* inits = tails + (size_t)NPAIR * NCHUNK;       // [NPAIR][NCHUNK]
    // ws needed: 2 * 128 * 3446 * 8 B ≈ 7.1 MB

    dim3 grid(BX, NCH);   // 14 x 64 = 896 blocks (capacity 4/CU * 256 = 1024)

    void* args[] = {(void*)&audio, (void*)&srp, (void*)&clp, (void*)&chp,
                    (void*)&tails, (void*)&inits, (void*)&out};
    hipError_t err = hipLaunchCooperativeKernel((const void*)k_fused, grid,
                                                dim3(256), args, 0, stream);
    if (err != hipSuccess) {
        (void)hipGetLastError();   // clear error, take the 3-kernel path
        hipLaunchKernelGGL((k_pass<false>), grid, dim3(256), 0, stream,
                           audio, srp, clp, chp, tails, nullptr, nullptr);
        hipLaunchKernelGGL(k_scan, dim3(NPAIR / 4), dim3(256), 0, stream,
                           srp, clp, chp, tails, inits);
        hipLaunchKernelGGL((k_pass<true>), grid, dim3(256), 0, stream,
                           audio, srp, clp, chp, nullptr, inits, out);
    }
}

// Round 2
// 439.544 us; speedup vs baseline: 1.3523x; 1.3523x over previous
//
#include <hip/hip_runtime.h>
#include <hip/hip_cooperative_groups.h>
#include <math.h>

// BandpassFilter: out = lowpass_biquad(x) - highpass_biquad(x), f32,
// shape (32,2,220500). Exact chunked-scan parallelization of the order-2 IIR.
//
// R4: fused cooperative kernel WITHOUT register-resident x. R3 post-mortem:
// xr[64] live across grid.sync() was demoted to scratch (VGPR_Count=64,
// WRITE_SIZE 254 MB = ~190 MB scratch traffic, 594 us). Fusion itself worked.
// Now both passes stage x via the proven R2 LDS path (coalesced float4,
// pad-33, zero bank conflicts); x's second read is L3-covered (56 MB < 256 MB
// Infinity Cache). The scan runs in-kernel between two grid.sync()s, so the
// ~78 us of scan-dispatch + inter-kernel gaps from the 3-kernel path is gone.
// Phase-C's first half is prefetched into LDS before grid.sync #1 so its
// staging hides under the scan barrier wait.
// Fallback to the proven 3-kernel path if cooperative launch is refused.

namespace cg = cooperative_groups;

namespace {

constexpr int T_LEN  = 220500;
constexpr int NCH    = 64;                          // 32 batch * 2 channels
constexpr int CHUNK  = 64;                          // samples per chunk
constexpr int NCHUNK = (T_LEN + CHUNK - 1) / CHUNK; // 3446 (last chunk = 20)
constexpr int NPAIR  = NCH * 2;                     // (channel, filter) pairs
constexpr int RUN    = (NCHUNK + 63) / 64;          // 54 chunk-elems per lane in scan
constexpr int CPB    = 256;                         // chunks per block
constexpr int BX     = (NCHUNK + CPB - 1) / CPB;    // 14 blocks along chunk dim
constexpr int HALF   = 32;                          // samples staged per tile
constexpr int LSTR   = HALF + 1;                    // 33: pad-1 -> conflict-free
constexpr int SCAN_BLOCKS = NPAIR / 4;              // 32 blocks x 4 waves = 128 waves

struct Coeffs { float b0, b1, b2, a1, a2; };

__device__ inline Coeffs make_coeffs(float sr, float cutoff, bool hp) {
    float w0 = 6.2831853071795864f * cutoff / sr;
    float c = cosf(w0), s = sinf(w0);
    float alpha = s / (2.0f * 0.707f);
    float b0, b1;
    if (!hp) { b0 = (1.0f - c) * 0.5f; b1 = 1.0f - c; }
    else     { b0 = (1.0f + c) * 0.5f; b1 = -(1.0f + c); }
    float inv = 1.0f / (1.0f + alpha);
    Coeffs k;
    k.b0 = b0 * inv; k.b1 = b1 * inv; k.b2 = b0 * inv;
    k.a1 = (-2.0f * c) * inv;
    k.a2 = (1.0f - alpha) * inv;
    return k;
}

// one sample through both filters; returns yl - yh
__device__ inline float proc_sample(float xn, float& x1, float& x2,
                                    const Coeffs& lo, const Coeffs& hi,
                                    float& yl1, float& yl2,
                                    float& yh1, float& yh2) {
    float ffl = fmaf(lo.b0, xn, fmaf(lo.b1, x1, lo.b2 * x2));
    float tl  = fmaf(-lo.a2, yl2, ffl);
    float yl  = fmaf(-lo.a1, yl1, tl);
    float ffh = fmaf(hi.b0, xn, fmaf(hi.b1, x1, hi.b2 * x2));
    float th  = fmaf(-hi.a2, yh2, ffh);
    float yh  = fmaf(-hi.a1, yh1, th);
    yl2 = yl1; yl1 = yl;
    yh2 = yh1; yh1 = yh;
    x2 = x1; x1 = xn;
    return yl - yh;
}

// Wave-level affine scan over one (channel, filter) pair's chunk tails.
__device__ inline void scan_pair(int gw, int lane, float sr,
                                 const float* __restrict__ clp,
                                 const float* __restrict__ chp,
                                 const float2* __restrict__ tails,
                                 float2* __restrict__ inits) {
    int f = gw & 1;
    Coeffs k = make_coeffs(sr, f ? (*chp) : (*clp), f != 0);

    // M^CHUNK via 6 squarings (CHUNK = 64)
    float m00 = -k.a1, m01 = -k.a2, m10 = 1.0f, m11 = 0.0f;
    #pragma unroll
    for (int i = 0; i < 6; ++i) {
        float t00 = fmaf(m00, m00, m01 * m10);
        float t01 = fmaf(m00, m01, m01 * m11);
        float t10 = fmaf(m10, m00, m11 * m10);
        float t11 = fmaf(m10, m01, m11 * m11);
        m00 = t00; m01 = t01; m10 = t10; m11 = t11;
    }

    const float2* __restrict__ tp = tails + (size_t)gw * NCHUNK;
    float2* __restrict__ ip = inits + (size_t)gw * NCHUNK;

    int s0 = lane * RUN;
    int s1 = min(s0 + RUN, NCHUNK);

    float A00 = 1.f, A01 = 0.f, A10 = 0.f, A11 = 1.f, c0 = 0.f, c1 = 0.f;
    for (int p = s0; p < s1; ++p) {
        float2 t = tp[p];
        float nA00 = fmaf(m00, A00, m01 * A10);
        float nA01 = fmaf(m00, A01, m01 * A11);
        float nA10 = fmaf(m10, A00, m11 * A10);
        float nA11 = fmaf(m10, A01, m11 * A11);
        float nc0  = fmaf(m00, c0, fmaf(m01, c1, t.x));
        float nc1  = fmaf(m10, c0, fmaf(m11, c1, t.y));
        A00 = nA00; A01 = nA01; A10 = nA10; A11 = nA11; c0 = nc0; c1 = nc1;
    }

    #pragma unroll
    for (int d = 1; d < 64; d <<= 1) {
        float pA00 = __shfl_up(A00, d);
        float pA01 = __shfl_up(A01, d);
        float pA10 = __shfl_up(A10, d);
        float pA11 = __shfl_up(A11, d);
        float pc0  = __shfl_up(c0, d);
        float pc1  = __shfl_up(c1, d);
        if (lane >= d) {
            float nA00 = fmaf(A00, pA00, A01 * pA10);
            float nA01 = fmaf(A00, pA01, A01 * pA11);
            float nA10 = fmaf(A10, pA00, A11 * pA10);
            float nA11 = fmaf(A10, pA01, A11 * pA11);
            float nc0  = fmaf(A00, pc0, fmaf(A01, pc1, c0));
            float nc1  = fmaf(A10, pc0, fmaf(A11, pc1, c1));
            A00 = nA00; A01 = nA01; A10 = nA10; A11 = nA11; c0 = nc0; c1 = nc1;
        }
    }
    float e0 = __shfl_up(c0, 1);
    float e1 = __shfl_up(c1, 1);
    if (lane == 0) { e0 = 0.0f; e1 = 0.0f; }

    float sA = e0, sB = e1;
    for (int p = s0; p < s1; ++p) {
        ip[p] = make_float2(sA, sB);
        float2 t = tp[p];
        float n0 = fmaf(m00, sA, fmaf(m01, sB, t.x));
        float n1 = fmaf(m10, sA, fmaf(m11, sB, t.y));
        sA = n0; sB = n1;
    }
}

// ---------------------------------------------------------------------------
// Fused cooperative kernel. No per-thread x array (R3 lesson: arrays live
// across grid.sync() spill to scratch). LDS 33,792 B + VGPR<=128 ->
// 4 blocks/CU -> co-residency capacity 1024 >= 896 launched.
// ---------------------------------------------------------------------------
__global__ __launch_bounds__(256, 4)
void k_fused(const float* __restrict__ x,
             const int* __restrict__ srp,
             const float* __restrict__ clp,
             const float* __restrict__ chp,
             float2* __restrict__ tails,
             float2* __restrict__ inits,
             float* __restrict__ out) {
    __shared__ float lds[CPB * LSTR];   // 33,792 B
    cg::grid_group grid = cg::this_grid();

    const int t   = threadIdx.x;
    const int ch  = blockIdx.y;
    const int bx  = blockIdx.x;
    const int pb  = bx * CPB;
    const int p   = pb + t;
    const int bid = ch * BX + bx;       // flat block id, 0..895

    float sr = (float)(*srp);
    Coeffs lo = make_coeffs(sr, *clp, false);
    Coeffs hi = make_coeffs(sr, *chp, true);

    const float* __restrict__ xc = x + (size_t)ch * T_LEN;
    const bool active = (p < NCHUNK);
    const int s = p * CHUNK;
    const int regBase = pb * CHUNK;

    // x history (2 scalar loads; lines become L2-hot from staging anyway)
    float x1 = (active && s >= 1) ? xc[s - 1] : 0.0f;
    float x2 = (active && s >= 2) ? xc[s - 2] : 0.0f;

    // stage half h of this block's region into LDS (coalesced float4 reads,
    // pad-33 transpose layout, OOB zero-filled so full-64 loops are safe).
    auto stage = [&](int h) {
        #pragma unroll
        for (int i = 0; i < (CPB * HALF) / (4 * 256); ++i) {   // 8 iters
            int f4 = i * 256 + t;
            int c  = f4 >> 3;
            int j0 = (f4 & 7) * 4;
            int g  = regBase + c * CHUNK + h * HALF + j0;
            float4 v = make_float4(0.f, 0.f, 0.f, 0.f);
            if (g < T_LEN) v = *(const float4*)(xc + g);   // T_LEN%4==0
            float* d = &lds[c * LSTR + j0];
            d[0] = v.x; d[1] = v.y; d[2] = v.z; d[3] = v.w;
        }
    };

    // ---- phase A: zero-state run, record 2-tap tails
    {
        float ax1 = x1, ax2 = x2;
        float yl1 = 0.f, yl2 = 0.f, yh1 = 0.f, yh2 = 0.f;
        #pragma unroll
        for (int h = 0; h < 2; ++h) {
            stage(h);
            __syncthreads();
            const float* __restrict__ L = &lds[t * LSTR];
            #pragma unroll
            for (int j = 0; j < HALF; ++j)
                (void)proc_sample(L[j], ax1, ax2, lo, hi, yl1, yl2, yh1, yh2);
            __syncthreads();   // LDS reuse by next stage
        }
        if (active) {
            tails[(size_t)(ch * 2 + 0) * NCHUNK + p] = make_float2(yl1, yl2);
            tails[(size_t)(ch * 2 + 1) * NCHUNK + p] = make_float2(yh1, yh2);
        }
    }

    // prefetch phase-C half 0 into LDS: hides under the scan barrier wait
    // (LDS is free here; everyone passed the post-compute __syncthreads).
    stage(0);

    __threadfence();      // make tails visible device-wide (cross-XCD)
    grid.sync();

    // ---- phase B: 128 scan waves (first 32 blocks); everyone else waits
    if (bid < SCAN_BLOCKS) {
        int gw   = bid * 4 + (t >> 6);   // 0..127
        int lane = t & 63;
        scan_pair(gw, lane, sr, clp, chp, tails, inits);
        __threadfence();  // make inits visible device-wide
    }
    grid.sync();
    __syncthreads();      // drain this block's prefetch ds_writes before reads

    // ---- phase C: exact run with scanned init states; y staged back
    // through LDS for coalesced float4 stores.
    float yl1 = 0.f, yl2 = 0.f, yh1 = 0.f, yh2 = 0.f;
    if (active) {
        float2 il = inits[(size_t)(ch * 2 + 0) * NCHUNK + p];
        float2 ih = inits[(size_t)(ch * 2 + 1) * NCHUNK + p];
        yl1 = il.x; yl2 = il.y; yh1 = ih.x; yh2 = ih.y;
    }
    float* __restrict__ oc = out + (size_t)ch * T_LEN;

    #pragma unroll
    for (int h = 0; h < 2; ++h) {
        if (h == 1) {      // half 0 was prefetched before the scan
            stage(1);
            __syncthreads();
        }
        {
            float* __restrict__ L = &lds[t * LSTR];
            #pragma unroll
            for (int j = 0; j < HALF; ++j)
                L[j] = proc_sample(L[j], x1, x2, lo, hi, yl1, yl2, yh1, yh2);
        }
        __syncthreads();
        #pragma unroll
        for (int i = 0; i < (CPB * HALF) / (4 * 256); ++i) {
            int f4 = i * 256 + t;
            int c  = f4 >> 3;
            int j0 = (f4 & 7) * 4;
            int g  = regBase + c * CHUNK + h * HALF + j0;
            if (g < T_LEN) {
                const float* sld = &lds[c * LSTR + j0];
                *(float4*)(oc + g) = make_float4(sld[0], sld[1], sld[2], sld[3]);
            }
        }
        __syncthreads();   // stores read LDS; protect before next stage
    }
}

// ---------------------------------------------------------------------------
// Fallback path (R2's proven 3-kernel pipeline) — used only if the
// cooperative launch is refused by the runtime.
// ---------------------------------------------------------------------------
template <bool FINAL>
__global__ __launch_bounds__(256)
void k_pass(const float* __restrict__ x,
            const int* __restrict__ srp,
            const float* __restrict__ clp,
            const float* __restrict__ chp,
            float2* __restrict__ tails,
            const float2* __restrict__ inits,
            float* __restrict__ out) {
    __shared__ float lds[CPB * LSTR];

    const int t  = threadIdx.x;
    const int ch = blockIdx.y;
    const int pb = blockIdx.x * CPB;
    const int p  = pb + t;

    float sr = (float)(*srp);
    Coeffs lo = make_coeffs(sr, *clp, false);
    Coeffs hi = make_coeffs(sr, *chp, true);

    const float* __restrict__ xc = x + (size_t)ch * T_LEN;
    float* __restrict__ oc = out + (size_t)ch * T_LEN;

    const bool active = (p < NCHUNK);
    const int s   = p * CHUNK;
    const int len = active ? min(CHUNK, T_LEN - s) : 0;

    float x1 = (active && s >= 1) ? xc[s - 1] : 0.0f;
    float x2 = (active && s >= 2) ? xc[s - 2] : 0.0f;
    float yl1 = 0.0f, yl2 = 0.0f, yh1 = 0.0f, yh2 = 0.0f;
    if (FINAL && active) {
        float2 il = inits[(size_t)(ch * 2 + 0) * NCHUNK + p];
        float2 ih = inits[(size_t)(ch * 2 + 1) * NCHUNK + p];
        yl1 = il.x; yl2 = il.y; yh1 = ih.x; yh2 = ih.y;
    }

    const int regBase = pb * CHUNK;

    #pragma unroll
    for (int h = 0; h < 2; ++h) {
        #pragma unroll
        for (int i = 0; i < (CPB * HALF) / (4 * 256); ++i) {
            int f4 = i * 256 + t;
            int c  = f4 >> 3;
            int j0 = (f4 & 7) * 4;
            int g  = regBase + c * CHUNK + h * HALF + j0;
            if (g < T_LEN) {
                float4 v = *(const float4*)(xc + g);
                float* d = &lds[c * LSTR + j0];
                d[0] = v.x; d[1] = v.y; d[2] = v.z; d[3] = v.w;
            }
        }
        __syncthreads();

        {
            int n = len - h * HALF;
            if (n > HALF) n = HALF;
            float* __restrict__ L = &lds[t * LSTR];
            if (n == HALF) {
                #pragma unroll
                for (int j = 0; j < HALF; ++j) {
                    float y = proc_sample(L[j], x1, x2, lo, hi, yl1, yl2, yh1, yh2);
                    if (FINAL) L[j] = y;
                }
            } else {
                for (int j = 0; j < n; ++j) {
                    float y = proc_sample(L[j], x1, x2, lo, hi, yl1, yl2, yh1, yh2);
                    if (FINAL) L[j] = y;
                }
            }
        }
        __syncthreads();

        if (FINAL) {
            #pragma unroll
            for (int i = 0; i < (CPB * HALF) / (4 * 256); ++i) {
                int f4 = i * 256 + t;
                int c  = f4 >> 3;
                int j0 = (f4 & 7) * 4;
                int g  = regBase + c * CHUNK + h * HALF + j0;
                if (g < T_LEN) {
                    const float* sld = &lds[c * LSTR + j0];
                    float4 v = make_float4(sld[0], sld[1], sld[2], sld[3]);
                    *(float4*)(oc + g) = v;
                }
            }
            __syncthreads();
        }
    }

    if (!FINAL && active) {
        tails[(size_t)(ch * 2 + 0) * NCHUNK + p] = make_float2(yl1, yl2);
        tails[(size_t)(ch * 2 + 1) * NCHUNK + p] = make_float2(yh1, yh2);
    }
}

__global__ __launch_bounds__(256)
void k_scan(const int* __restrict__ srp,
            const float* __restrict__ clp,
            const float* __restrict__ chp,
            const float2* __restrict__ tails,
            float2* __restrict__ inits) {
    int gtid = blockIdx.x * 256 + threadIdx.x;
    int wid  = gtid >> 6;
    int lane = threadIdx.x & 63;
    float sr = (float)(*srp);
    scan_pair(wid, lane, sr, clp, chp, tails, inits);
}

} // namespace

extern "C" void kernel_launch(void* const* d_in, const int* in_sizes, int n_in,
                              void* d_out, int out_size, void* d_ws, size_t ws_size,
                              hipStream_t stream) {
    const float* audio = (const float*)d_in[0];
    const int*   srp   = (const int*)d_in[1];
    const float* clp   = (const float*)d_in[2];
    const float* chp   = (const float*)d_in[3];
    float* out = (float*)d_out;

    float2* tails = (float2*)d_ws;                        // [NPAIR][NCHUNK]
    float2* inits = tails + (size_t)NPAIR * NCHUNK;       // [NPAIR][NCHUNK]
    // ws needed: 2 * 128 * 3446 * 8 B ≈ 7.1 MB

    dim3 grid(BX, NCH);   // 14 x 64 = 896 blocks (capacity 4/CU * 256 = 1024)

    void* args[] = {(void*)&audio, (void*)&srp, (void*)&clp, (void*)&chp,
                    (void*)&tails, (void*)&inits, (void*)&out};
    hipError_t err = hipLaunchCooperativeKernel((const void*)k_fused, grid,
                                                dim3(256), args, 0, stream);
    if (err != hipSuccess) {
        (void)hipGetLastError();   // clear error, take the 3-kernel path
        hipLaunchKernelGGL((k_pass<false>), grid, dim3(256), 0, stream,
                           audio, srp, clp, chp, tails, nullptr, nullptr);
        hipLaunchKernelGGL(k_scan, dim3(NPAIR / 4), dim3(256), 0, stream,
                           srp, clp, chp, tails, inits);
        hipLaunchKernelGGL((k_pass<true>), grid, dim3(256), 0, stream,
                           audio, srp, clp, chp, nullptr, inits, out);
    }
}

// Round 3
// 176.432 us; speedup vs baseline: 3.3690x; 2.4913x over previous
//
#include <hip/hip_runtime.h>
#include <math.h>

// BandpassFilter: out = lowpass_biquad(x) - highpass_biquad(x), f32,
// shape (32,2,220500). Exact chunked-scan parallelization of the order-2 IIR.
//
// R5: single-pass chained scan with decoupled lookback (rocPRIM-style).
// R4 post-mortem: cg::grid.sync() on 896 blocks costs ~100 us each (kernel
// 308 us with VALUBusy 3.7%, HBM 7% - pure barrier wait). But the dependency
// is only along bx within a channel (<=13 predecessors), so no grid barrier
// is needed: each block computes its local affine aggregate (tails stay in
// REGISTERS - no global tails/inits traffic at all), publishes it with a
// device-scope release flag, and polls its <=13 predecessors' aggregates
// (published concurrently -> wait ~= phase-A skew, not a serial chain).
// Deadlock-safe by CAPACITY, not dispatch order: 896 blocks @ 34.9 KB LDS,
// <=128 VGPR = 4 blocks/CU -> 1024 resident slots >= 896 (R4's successful
// cooperative launch is HW proof of co-residency at this footprint).
// Flags zeroed by in-stream hipMemsetAsync (graph-capturable).

namespace {

constexpr int T_LEN  = 220500;
constexpr int NCH    = 64;                          // 32 batch * 2 channels
constexpr int CHUNK  = 64;                          // samples per chunk
constexpr int NCHUNK = (T_LEN + CHUNK - 1) / CHUNK; // 3446 (last chunk = 20)
constexpr int CPB    = 256;                         // chunks per block
constexpr int BX     = (NCHUNK + CPB - 1) / CPB;    // 14 blocks along chunk dim
constexpr int NBLK   = BX * NCH;                    // 896 blocks
constexpr int HALF   = 32;                          // samples staged per tile
constexpr int LSTR   = HALF + 1;                    // 33: pad-1 -> conflict-free

struct Coeffs { float b0, b1, b2, a1, a2; };

__device__ inline Coeffs make_coeffs(float sr, float cutoff, bool hp) {
    float w0 = 6.2831853071795864f * cutoff / sr;
    float c = cosf(w0), s = sinf(w0);
    float alpha = s / (2.0f * 0.707f);
    float b0, b1;
    if (!hp) { b0 = (1.0f - c) * 0.5f; b1 = 1.0f - c; }
    else     { b0 = (1.0f + c) * 0.5f; b1 = -(1.0f + c); }
    float inv = 1.0f / (1.0f + alpha);
    Coeffs k;
    k.b0 = b0 * inv; k.b1 = b1 * inv; k.b2 = b0 * inv;
    k.a1 = (-2.0f * c) * inv;
    k.a2 = (1.0f - alpha) * inv;
    return k;
}

// one sample through both filters; returns yl - yh
__device__ inline float proc_sample(float xn, float& x1, float& x2,
                                    const Coeffs& lo, const Coeffs& hi,
                                    float& yl1, float& yl2,
                                    float& yh1, float& yh2) {
    float ffl = fmaf(lo.b0, xn, fmaf(lo.b1, x1, lo.b2 * x2));
    float tl  = fmaf(-lo.a2, yl2, ffl);
    float yl  = fmaf(-lo.a1, yl1, tl);
    float ffh = fmaf(hi.b0, xn, fmaf(hi.b1, x1, hi.b2 * x2));
    float th  = fmaf(-hi.a2, yh2, ffh);
    float yh  = fmaf(-hi.a1, yh1, th);
    yl2 = yl1; yl1 = yl;
    yh2 = yh1; yh1 = yh;
    x2 = x1; x1 = xn;
    return yl - yh;
}

// Affine map s' = A*s + c on the 2-tap IIR state s = (y[n-1], y[n-2]).
struct Aff { float a00, a01, a10, a11, c0, c1; };

__device__ inline Aff aff_id() { return {1.f, 0.f, 0.f, 1.f, 0.f, 0.f}; }

// g o f : f applied first. Same formulas as the R2-verified scan.
__device__ inline Aff aff_compose(const Aff& g, const Aff& f) {
    Aff r;
    r.a00 = fmaf(g.a00, f.a00, g.a01 * f.a10);
    r.a01 = fmaf(g.a00, f.a01, g.a01 * f.a11);
    r.a10 = fmaf(g.a10, f.a00, g.a11 * f.a10);
    r.a11 = fmaf(g.a10, f.a01, g.a11 * f.a11);
    r.c0  = fmaf(g.a00, f.c0, fmaf(g.a01, f.c1, g.c0));
    r.c1  = fmaf(g.a10, f.c0, fmaf(g.a11, f.c1, g.c1));
    return r;
}

__device__ inline Aff aff_shfl_up(const Aff& e, int d) {
    Aff p;
    p.a00 = __shfl_up(e.a00, d);
    p.a01 = __shfl_up(e.a01, d);
    p.a10 = __shfl_up(e.a10, d);
    p.a11 = __shfl_up(e.a11, d);
    p.c0  = __shfl_up(e.c0, d);
    p.c1  = __shfl_up(e.c1, d);
    return p;
}

// M^CHUNK for one filter: chunk transition matrix, CHUNK=64 via 6 squarings.
__device__ inline void chunk_matrix(const Coeffs& k,
                                    float& m00, float& m01,
                                    float& m10, float& m11) {
    m00 = -k.a1; m01 = -k.a2; m10 = 1.0f; m11 = 0.0f;
    #pragma unroll
    for (int i = 0; i < 6; ++i) {
        float t00 = fmaf(m00, m00, m01 * m10);
        float t01 = fmaf(m00, m01, m01 * m11);
        float t10 = fmaf(m10, m00, m11 * m10);
        float t11 = fmaf(m10, m01, m11 * m11);
        m00 = t00; m01 = t01; m10 = t10; m11 = t11;
    }
}

__global__ __launch_bounds__(256, 4)
void k_bandpass(const float* __restrict__ x,
                const int* __restrict__ srp,
                const float* __restrict__ clp,
                const float* __restrict__ chp,
                float* __restrict__ agg,          // [NBLK][12] published aggregates
                unsigned int* __restrict__ flags, // [NBLK] 0=empty 1=ready
                float* __restrict__ out) {
    __shared__ float lds[CPB * LSTR];   // 33,792 B staging tile
    __shared__ Aff ldsWaveL[4], ldsWaveH[4];   // wave inclusive totals
    __shared__ Aff ldsWL[4],  ldsWH[4];        // wave exclusive prefixes
    __shared__ Aff ldsLBl[BX], ldsLBh[BX];     // lookback payloads
    __shared__ float ldsCB[4];                 // block entry state (lo, hi)

    const int t   = threadIdx.x;
    const int ch  = blockIdx.y;
    const int bx  = blockIdx.x;
    const int pb  = bx * CPB;
    const int p   = pb + t;
    const int bid = ch * BX + bx;

    float sr = (float)(*srp);
    Coeffs lo = make_coeffs(sr, *clp, false);
    Coeffs hi = make_coeffs(sr, *chp, true);

    const float* __restrict__ xc = x + (size_t)ch * T_LEN;
    const bool active = (p < NCHUNK);
    const int s = p * CHUNK;
    const int regBase = pb * CHUNK;

    // x history (exact; crosses chunk/block boundaries by direct global read)
    float x1 = (active && s >= 1) ? xc[s - 1] : 0.0f;
    float x2 = (active && s >= 2) ? xc[s - 2] : 0.0f;

    // stage half h (proven R2 path: coalesced float4, pad-33, 0 conflicts)
    auto stage = [&](int h) {
        #pragma unroll
        for (int i = 0; i < (CPB * HALF) / (4 * 256); ++i) {   // 8 iters
            int f4 = i * 256 + t;
            int c  = f4 >> 3;
            int j0 = (f4 & 7) * 4;
            int g  = regBase + c * CHUNK + h * HALF + j0;
            if (g < T_LEN) {                                   // T_LEN%4==0
                float4 v = *(const float4*)(xc + g);
                float* d = &lds[c * LSTR + j0];
                d[0] = v.x; d[1] = v.y; d[2] = v.z; d[3] = v.w;
            }
        }
    };

    // ---- phase A: zero-state run, tails kept in registers
    float tl1 = 0.f, tl2 = 0.f, th1 = 0.f, th2 = 0.f;
    {
        float ax1 = x1, ax2 = x2;
        #pragma unroll
        for (int h = 0; h < 2; ++h) {
            stage(h);
            __syncthreads();
            const float* __restrict__ L = &lds[t * LSTR];
            #pragma unroll
            for (int j = 0; j < HALF; ++j)
                (void)proc_sample(L[j], ax1, ax2, lo, hi, tl1, tl2, th1, th2);
            __syncthreads();
        }
    }
    // (junk in the short last chunk's tail is never consumed: it has no
    //  successor chunk anywhere, and block BX-1's aggregate is never polled)

    // ---- block-level affine scan over the 256 per-chunk maps
    float Ml00, Ml01, Ml10, Ml11, Mh00, Mh01, Mh10, Mh11;
    chunk_matrix(lo, Ml00, Ml01, Ml10, Ml11);
    chunk_matrix(hi, Mh00, Mh01, Mh10, Mh11);

    Aff il = active ? Aff{Ml00, Ml01, Ml10, Ml11, tl1, tl2} : aff_id();
    Aff ih = active ? Aff{Mh00, Mh01, Mh10, Mh11, th1, th2} : aff_id();

    const int lane = t & 63;
    const int w    = t >> 6;

    // wave inclusive scan (Hillis-Steele, verified compose order cur o prev)
    #pragma unroll
    for (int d = 1; d < 64; d <<= 1) {
        Aff plx = aff_shfl_up(il, d);
        Aff phx = aff_shfl_up(ih, d);
        if (lane >= d) {
            il = aff_compose(il, plx);
            ih = aff_compose(ih, phx);
        }
    }
    if (lane == 63) { ldsWaveL[w] = il; ldsWaveH[w] = ih; }
    __syncthreads();

    if (t == 0) {
        Aff rl = aff_id(), rh = aff_id();
        #pragma unroll
        for (int ww = 0; ww < 4; ++ww) {
            ldsWL[ww] = rl; ldsWH[ww] = rh;
            rl = aff_compose(ldsWaveL[ww], rl);
            rh = aff_compose(ldsWaveH[ww], rh);
        }
        // rl/rh = block inclusive aggregate -> publish (release, agent scope)
        float* pl = agg + (size_t)bid * 12;
        __hip_atomic_store(pl + 0,  rl.a00, __ATOMIC_RELAXED, __HIP_MEMORY_SCOPE_AGENT);
        __hip_atomic_store(pl + 1,  rl.a01, __ATOMIC_RELAXED, __HIP_MEMORY_SCOPE_AGENT);
        __hip_atomic_store(pl + 2,  rl.a10, __ATOMIC_RELAXED, __HIP_MEMORY_SCOPE_AGENT);
        __hip_atomic_store(pl + 3,  rl.a11, __ATOMIC_RELAXED, __HIP_MEMORY_SCOPE_AGENT);
        __hip_atomic_store(pl + 4,  rl.c0,  __ATOMIC_RELAXED, __HIP_MEMORY_SCOPE_AGENT);
        __hip_atomic_store(pl + 5,  rl.c1,  __ATOMIC_RELAXED, __HIP_MEMORY_SCOPE_AGENT);
        __hip_atomic_store(pl + 6,  rh.a00, __ATOMIC_RELAXED, __HIP_MEMORY_SCOPE_AGENT);
        __hip_atomic_store(pl + 7,  rh.a01, __ATOMIC_RELAXED, __HIP_MEMORY_SCOPE_AGENT);
        __hip_atomic_store(pl + 8,  rh.a10, __ATOMIC_RELAXED, __HIP_MEMORY_SCOPE_AGENT);
        __hip_atomic_store(pl + 9,  rh.a11, __ATOMIC_RELAXED, __HIP_MEMORY_SCOPE_AGENT);
        __hip_atomic_store(pl + 10, rh.c0,  __ATOMIC_RELAXED, __HIP_MEMORY_SCOPE_AGENT);
        __hip_atomic_store(pl + 11, rh.c1,  __ATOMIC_RELAXED, __HIP_MEMORY_SCOPE_AGENT);
        __hip_atomic_store(&flags[bid], 1u, __ATOMIC_RELEASE, __HIP_MEMORY_SCOPE_AGENT);
    }
    __syncthreads();

    // per-thread block-exclusive prefix = (wave-exclusive of thread) o W[wave]
    Aff exL, exH;
    {
        Aff pl_ = aff_shfl_up(il, 1);
        Aff ph_ = aff_shfl_up(ih, 1);
        if (lane == 0) { pl_ = aff_id(); ph_ = aff_id(); }
        exL = aff_compose(pl_, ldsWL[w]);
        exH = aff_compose(ph_, ldsWH[w]);
    }

    // ---- lookback: wave 0 polls the <=13 predecessors of this channel
    if (bx > 0) {
        if (t < bx) {   // lanes 0..bx-1 of wave 0
            int idx = ch * BX + t;
            while (__hip_atomic_load(&flags[idx], __ATOMIC_ACQUIRE,
                                     __HIP_MEMORY_SCOPE_AGENT) == 0u)
                __builtin_amdgcn_s_sleep(4);
            const float* pp = agg + (size_t)idx * 12;
            Aff al, ah;
            al.a00 = __hip_atomic_load(pp + 0,  __ATOMIC_RELAXED, __HIP_MEMORY_SCOPE_AGENT);
            al.a01 = __hip_atomic_load(pp + 1,  __ATOMIC_RELAXED, __HIP_MEMORY_SCOPE_AGENT);
            al.a10 = __hip_atomic_load(pp + 2,  __ATOMIC_RELAXED, __HIP_MEMORY_SCOPE_AGENT);
            al.a11 = __hip_atomic_load(pp + 3,  __ATOMIC_RELAXED, __HIP_MEMORY_SCOPE_AGENT);
            al.c0  = __hip_atomic_load(pp + 4,  __ATOMIC_RELAXED, __HIP_MEMORY_SCOPE_AGENT);
            al.c1  = __hip_atomic_load(pp + 5,  __ATOMIC_RELAXED, __HIP_MEMORY_SCOPE_AGENT);
            ah.a00 = __hip_atomic_load(pp + 6,  __ATOMIC_RELAXED, __HIP_MEMORY_SCOPE_AGENT);
            ah.a01 = __hip_atomic_load(pp + 7,  __ATOMIC_RELAXED, __HIP_MEMORY_SCOPE_AGENT);
            ah.a10 = __hip_atomic_load(pp + 8,  __ATOMIC_RELAXED, __HIP_MEMORY_SCOPE_AGENT);
            ah.a11 = __hip_atomic_load(pp + 9,  __ATOMIC_RELAXED, __HIP_MEMORY_SCOPE_AGENT);
            ah.c0  = __hip_atomic_load(pp + 10, __ATOMIC_RELAXED, __HIP_MEMORY_SCOPE_AGENT);
            ah.c1  = __hip_atomic_load(pp + 11, __ATOMIC_RELAXED, __HIP_MEMORY_SCOPE_AGENT);
            ldsLBl[t] = al; ldsLBh[t] = ah;
        }
        __syncthreads();
        if (t == 0) {
            Aff rl = ldsLBl[0], rh = ldsLBh[0];
            for (int l = 1; l < bx; ++l) {
                rl = aff_compose(ldsLBl[l], rl);
                rh = aff_compose(ldsLBh[l], rh);
            }
            ldsCB[0] = rl.c0; ldsCB[1] = rl.c1;   // entry state = prefix(0)
            ldsCB[2] = rh.c0; ldsCB[3] = rh.c1;
        }
        __syncthreads();
    } else if (t == 0) {
        ldsCB[0] = 0.f; ldsCB[1] = 0.f; ldsCB[2] = 0.f; ldsCB[3] = 0.f;
    }
    if (bx == 0) __syncthreads();

    const float cbl0 = ldsCB[0], cbl1 = ldsCB[1];
    const float cbh0 = ldsCB[2], cbh1 = ldsCB[3];

    // exact init state for this thread's chunk: ex(cb)
    float yl1 = fmaf(exL.a00, cbl0, fmaf(exL.a01, cbl1, exL.c0));
    float yl2 = fmaf(exL.a10, cbl0, fmaf(exL.a11, cbl1, exL.c1));
    float yh1 = fmaf(exH.a00, cbh0, fmaf(exH.a01, cbh1, exH.c0));
    float yh2 = fmaf(exH.a10, cbh0, fmaf(exH.a11, cbh1, exH.c1));

    // ---- phase C: exact run; x restaged (block's own region: L2/L3-hot),
    // y staged back through LDS for coalesced float4 stores.
    float* __restrict__ oc = out + (size_t)ch * T_LEN;

    #pragma unroll
    for (int h = 0; h < 2; ++h) {
        stage(h);
        __syncthreads();
        {
            float* __restrict__ L = &lds[t * LSTR];
            #pragma unroll
            for (int j = 0; j < HALF; ++j)
                L[j] = proc_sample(L[j], x1, x2, lo, hi, yl1, yl2, yh1, yh2);
        }
        __syncthreads();
        #pragma unroll
        for (int i = 0; i < (CPB * HALF) / (4 * 256); ++i) {
            int f4 = i * 256 + t;
            int c  = f4 >> 3;
            int j0 = (f4 & 7) * 4;
            int g  = regBase + c * CHUNK + h * HALF + j0;
            if (g < T_LEN) {
                const float* sld = &lds[c * LSTR + j0];
                *(float4*)(oc + g) = make_float4(sld[0], sld[1], sld[2], sld[3]);
            }
        }
        __syncthreads();   // stores read LDS; protect before next stage
    }
}

} // namespace

extern "C" void kernel_launch(void* const* d_in, const int* in_sizes, int n_in,
                              void* d_out, int out_size, void* d_ws, size_t ws_size,
                              hipStream_t stream) {
    const float* audio = (const float*)d_in[0];
    const int*   srp   = (const int*)d_in[1];
    const float* clp   = (const float*)d_in[2];
    const float* chp   = (const float*)d_in[3];
    float* out = (float*)d_out;

    // ws layout: [NBLK] u32 flags | pad to 4096 B | [NBLK][12] f32 aggregates
    unsigned int* flags = (unsigned int*)d_ws;
    float* agg = (float*)((char*)d_ws + 4096);
    // ws needed: 4096 + 896*48 B ~= 47 KB

    hipMemsetAsync(flags, 0, NBLK * sizeof(unsigned int), stream);

    dim3 grid(BX, NCH);   // 14 x 64 = 896 blocks; capacity 4/CU * 256 = 1024
    hipLaunchKernelGGL(k_bandpass, grid, dim3(256), 0, stream,
                       audio, srp, clp, chp, agg, flags, out);
}

// Round 4
// 171.770 us; speedup vs baseline: 3.4605x; 1.0271x over previous
//
#include <hip/hip_runtime.h>
#include <math.h>

// BandpassFilter: out = lowpass_biquad(x) - highpass_biquad(x), f32,
// shape (32,2,220500). Exact chunked-scan parallelization of the order-2 IIR.
//
// R6: contiguous-group staging + reg-prefetch on the R5 lookback skeleton.
// R5 post-mortem: kernel 95 us = exactly 2x a single R2 pass (46 us); scan+
// lookback cost ~0. Each pass was limited by the half-tile staging pattern:
// 128-B segments strided 256 B on BOTH reads and writes (DRAM-burst hostile,
// ~2.7 TB/s ceiling) and zero stage/compute overlap. Now the block's 256
// chunks are processed as two groups of 128 CONSECUTIVE chunks: every global
// access is a fully linear 32-KB burst; LDS tile [128][65] gives <=2-way
// (free) bank aliasing on all paths. A single float4 r[8] register buffer
// (static indexing) prefetches the next group's x under the current group's
// compute, and phase-C G0's loads are issued before the scan/lookback so
// they land under the spin wait. Lookback spin now polls with relaxed
// SYSTEM-scope loads (no per-iteration cache invalidate; reads the coherence
// point) with a hang-proof fallback to the proven acquire-AGENT load.

namespace {

constexpr int T_LEN  = 220500;
constexpr int NCH    = 64;                          // 32 batch * 2 channels
constexpr int CHUNK  = 64;                          // samples per chunk
constexpr int NCHUNK = (T_LEN + CHUNK - 1) / CHUNK; // 3446 (last chunk = 20)
constexpr int CPB    = 256;                         // chunks per block
constexpr int BX     = (NCHUNK + CPB - 1) / CPB;    // 14 blocks along chunk dim
constexpr int NBLK   = BX * NCH;                    // 896 blocks
constexpr int GCH    = 128;                         // chunks per group (2 groups)
constexpr int GFLT   = GCH * CHUNK;                 // 8192 floats = 32 KB/group
constexpr int LSTR   = CHUNK + 1;                   // 65: pad-1, <=2-way banks

struct Coeffs { float b0, b1, b2, a1, a2; };

__device__ inline Coeffs make_coeffs(float sr, float cutoff, bool hp) {
    float w0 = 6.2831853071795864f * cutoff / sr;
    float c = cosf(w0), s = sinf(w0);
    float alpha = s / (2.0f * 0.707f);
    float b0, b1;
    if (!hp) { b0 = (1.0f - c) * 0.5f; b1 = 1.0f - c; }
    else     { b0 = (1.0f + c) * 0.5f; b1 = -(1.0f + c); }
    float inv = 1.0f / (1.0f + alpha);
    Coeffs k;
    k.b0 = b0 * inv; k.b1 = b1 * inv; k.b2 = b0 * inv;
    k.a1 = (-2.0f * c) * inv;
    k.a2 = (1.0f - alpha) * inv;
    return k;
}

// one sample through both filters; returns yl - yh
__device__ inline float proc_sample(float xn, float& x1, float& x2,
                                    const Coeffs& lo, const Coeffs& hi,
                                    float& yl1, float& yl2,
                                    float& yh1, float& yh2) {
    float ffl = fmaf(lo.b0, xn, fmaf(lo.b1, x1, lo.b2 * x2));
    float tl  = fmaf(-lo.a2, yl2, ffl);
    float yl  = fmaf(-lo.a1, yl1, tl);
    float ffh = fmaf(hi.b0, xn, fmaf(hi.b1, x1, hi.b2 * x2));
    float th  = fmaf(-hi.a2, yh2, ffh);
    float yh  = fmaf(-hi.a1, yh1, th);
    yl2 = yl1; yl1 = yl;
    yh2 = yh1; yh1 = yh;
    x2 = x1; x1 = xn;
    return yl - yh;
}

// Affine map s' = A*s + c on the 2-tap IIR state s = (y[n-1], y[n-2]).
struct Aff { float a00, a01, a10, a11, c0, c1; };

__device__ inline Aff aff_id() { return {1.f, 0.f, 0.f, 1.f, 0.f, 0.f}; }

// g o f : f applied first. Same formulas as the R2/R5-verified scan.
__device__ inline Aff aff_compose(const Aff& g, const Aff& f) {
    Aff r;
    r.a00 = fmaf(g.a00, f.a00, g.a01 * f.a10);
    r.a01 = fmaf(g.a00, f.a01, g.a01 * f.a11);
    r.a10 = fmaf(g.a10, f.a00, g.a11 * f.a10);
    r.a11 = fmaf(g.a10, f.a01, g.a11 * f.a11);
    r.c0  = fmaf(g.a00, f.c0, fmaf(g.a01, f.c1, g.c0));
    r.c1  = fmaf(g.a10, f.c0, fmaf(g.a11, f.c1, g.c1));
    return r;
}

__device__ inline Aff aff_shfl_up(const Aff& e, int d) {
    Aff p;
    p.a00 = __shfl_up(e.a00, d);
    p.a01 = __shfl_up(e.a01, d);
    p.a10 = __shfl_up(e.a10, d);
    p.a11 = __shfl_up(e.a11, d);
    p.c0  = __shfl_up(e.c0, d);
    p.c1  = __shfl_up(e.c1, d);
    return p;
}

// M^CHUNK for one filter: chunk transition matrix, CHUNK=64 via 6 squarings.
__device__ inline void chunk_matrix(const Coeffs& k,
                                    float& m00, float& m01,
                                    float& m10, float& m11) {
    m00 = -k.a1; m01 = -k.a2; m10 = 1.0f; m11 = 0.0f;
    #pragma unroll
    for (int i = 0; i < 6; ++i) {
        float t00 = fmaf(m00, m00, m01 * m10);
        float t01 = fmaf(m00, m01, m01 * m11);
        float t10 = fmaf(m10, m00, m11 * m10);
        float t11 = fmaf(m10, m01, m11 * m11);
        m00 = t00; m01 = t01; m10 = t10; m11 = t11;
    }
}

__global__ __launch_bounds__(256, 4)
void k_bandpass(const float* __restrict__ x,
                const int* __restrict__ srp,
                const float* __restrict__ clp,
                const float* __restrict__ chp,
                float* __restrict__ agg,          // [NBLK][12] published aggregates
                unsigned int* __restrict__ flags, // [NBLK] 0=empty 1=ready
                float* __restrict__ out) {
    __shared__ float lds[GCH * LSTR];          // 33,280 B group tile
    __shared__ Aff ldsWaveL[4], ldsWaveH[4];   // wave inclusive totals
    __shared__ Aff ldsWL[4],  ldsWH[4];        // wave exclusive prefixes
    __shared__ Aff ldsLBl[BX], ldsLBh[BX];     // lookback payloads
    __shared__ float ldsCB[4];                 // block entry state (lo, hi)

    const int t   = threadIdx.x;
    const int ch  = blockIdx.y;
    const int bx  = blockIdx.x;
    const int pb  = bx * CPB;
    const int p   = pb + t;
    const int bid = ch * BX + bx;

    float sr = (float)(*srp);
    Coeffs lo = make_coeffs(sr, *clp, false);
    Coeffs hi = make_coeffs(sr, *chp, true);

    const float* __restrict__ xc = x + (size_t)ch * T_LEN;
    const bool active = (p < NCHUNK);
    const int s = p * CHUNK;
    const int regBase = pb * CHUNK;

    // x history (exact; crosses chunk/block boundaries by direct global read)
    float x1 = (active && s >= 1) ? xc[s - 1] : 0.0f;
    float x2 = (active && s >= 2) ? xc[s - 2] : 0.0f;

    // ---- contiguous group staging primitives -----------------------------
    // group g = local chunks [g*128, g*128+128) = floats [g*GFLT, +GFLT):
    // fully linear 32-KB global bursts; OOB zero-filled (exactness: only the
    // last chunk's unused tail / never-stored region is padded).
    float4 r[8];   // reg prefetch buffer; all indexing compile-time constant

    auto ldreg = [&](int g) {
        #pragma unroll
        for (int i = 0; i < 8; ++i) {
            int f4 = i * 256 + t;
            int ga = regBase + g * GFLT + f4 * 4;
            if (ga < T_LEN) r[i] = *(const float4*)(xc + ga);  // T_LEN%4==0
            else            r[i] = make_float4(0.f, 0.f, 0.f, 0.f);
        }
    };
    auto wreg = [&]() {
        #pragma unroll
        for (int i = 0; i < 8; ++i) {
            int f4 = i * 256 + t;
            int c  = f4 >> 4;          // local chunk row 0..127
            int j0 = (f4 & 15) * 4;    // sample offset in chunk
            float* d = &lds[c * LSTR + j0];
            d[0] = r[i].x; d[1] = r[i].y; d[2] = r[i].z; d[3] = r[i].w;
        }
    };

    // ---- phase A: zero-state run, tails kept in registers ---------------
    float tl1 = 0.f, tl2 = 0.f, th1 = 0.f, th2 = 0.f;
    float ax1 = x1, ax2 = x2;

    ldreg(0);
    wreg();
    __syncthreads();
    ldreg(1);                          // in flight under G0 compute
    if ((t >> 7) == 0) {
        const float* __restrict__ L = &lds[(t & 127) * LSTR];
        #pragma unroll
        for (int j = 0; j < CHUNK; ++j)
            (void)proc_sample(L[j], ax1, ax2, lo, hi, tl1, tl2, th1, th2);
    }
    __syncthreads();
    wreg();
    __syncthreads();
    ldreg(0);                          // phase-C G0 prefetch: lands under scan
    if ((t >> 7) == 1) {
        const float* __restrict__ L = &lds[(t & 127) * LSTR];
        #pragma unroll
        for (int j = 0; j < CHUNK; ++j)
            (void)proc_sample(L[j], ax1, ax2, lo, hi, tl1, tl2, th1, th2);
    }

    // ---- block-level affine scan over the 256 per-chunk maps ------------
    float Ml00, Ml01, Ml10, Ml11, Mh00, Mh01, Mh10, Mh11;
    chunk_matrix(lo, Ml00, Ml01, Ml10, Ml11);
    chunk_matrix(hi, Mh00, Mh01, Mh10, Mh11);

    Aff il = active ? Aff{Ml00, Ml01, Ml10, Ml11, tl1, tl2} : aff_id();
    Aff ih = active ? Aff{Mh00, Mh01, Mh10, Mh11, th1, th2} : aff_id();

    const int lane = t & 63;
    const int w    = t >> 6;

    #pragma unroll
    for (int d = 1; d < 64; d <<= 1) {
        Aff plx = aff_shfl_up(il, d);
        Aff phx = aff_shfl_up(ih, d);
        if (lane >= d) {
            il = aff_compose(il, plx);
            ih = aff_compose(ih, phx);
        }
    }
    if (lane == 63) { ldsWaveL[w] = il; ldsWaveH[w] = ih; }
    __syncthreads();

    if (t == 0) {
        Aff rl = aff_id(), rh = aff_id();
        #pragma unroll
        for (int ww = 0; ww < 4; ++ww) {
            ldsWL[ww] = rl; ldsWH[ww] = rh;
            rl = aff_compose(ldsWaveL[ww], rl);
            rh = aff_compose(ldsWaveH[ww], rh);
        }
        // publish block aggregate (proven R5 protocol: relaxed payload +
        // release flag, agent scope)
        float* pl = agg + (size_t)bid * 12;
        __hip_atomic_store(pl + 0,  rl.a00, __ATOMIC_RELAXED, __HIP_MEMORY_SCOPE_AGENT);
        __hip_atomic_store(pl + 1,  rl.a01, __ATOMIC_RELAXED, __HIP_MEMORY_SCOPE_AGENT);
        __hip_atomic_store(pl + 2,  rl.a10, __ATOMIC_RELAXED, __HIP_MEMORY_SCOPE_AGENT);
        __hip_atomic_store(pl + 3,  rl.a11, __ATOMIC_RELAXED, __HIP_MEMORY_SCOPE_AGENT);
        __hip_atomic_store(pl + 4,  rl.c0,  __ATOMIC_RELAXED, __HIP_MEMORY_SCOPE_AGENT);
        __hip_atomic_store(pl + 5,  rl.c1,  __ATOMIC_RELAXED, __HIP_MEMORY_SCOPE_AGENT);
        __hip_atomic_store(pl + 6,  rh.a00, __ATOMIC_RELAXED, __HIP_MEMORY_SCOPE_AGENT);
        __hip_atomic_store(pl + 7,  rh.a01, __ATOMIC_RELAXED, __HIP_MEMORY_SCOPE_AGENT);
        __hip_atomic_store(pl + 8,  rh.a10, __ATOMIC_RELAXED, __HIP_MEMORY_SCOPE_AGENT);
        __hip_atomic_store(pl + 9,  rh.a11, __ATOMIC_RELAXED, __HIP_MEMORY_SCOPE_AGENT);
        __hip_atomic_store(pl + 10, rh.c0,  __ATOMIC_RELAXED, __HIP_MEMORY_SCOPE_AGENT);
        __hip_atomic_store(pl + 11, rh.c1,  __ATOMIC_RELAXED, __HIP_MEMORY_SCOPE_AGENT);
        __hip_atomic_store(&flags[bid], 1u, __ATOMIC_RELEASE, __HIP_MEMORY_SCOPE_AGENT);
    }
    __syncthreads();

    // per-thread block-exclusive prefix = (wave-exclusive of thread) o W[wave]
    Aff exL, exH;
    {
        Aff pl_ = aff_shfl_up(il, 1);
        Aff ph_ = aff_shfl_up(ih, 1);
        if (lane == 0) { pl_ = aff_id(); ph_ = aff_id(); }
        exL = aff_compose(pl_, ldsWL[w]);
        exH = aff_compose(ph_, ldsWH[w]);
    }

    // ---- lookback: wave 0 polls the <=13 predecessors of this channel ----
    if (bx > 0) {
        if (t < bx) {   // lanes 0..bx-1 of wave 0
            int idx = ch * BX + t;
            // cache-neutral spin: relaxed SYSTEM loads read the coherence
            // point without invalidating L1/L2 each iteration; hang-proof
            // fallback to the proven acquire-AGENT load after 1024 spins.
            int spins = 0;
            for (;;) {
                unsigned int f = (spins < 1024)
                    ? __hip_atomic_load(&flags[idx], __ATOMIC_RELAXED,
                                        __HIP_MEMORY_SCOPE_SYSTEM)
                    : __hip_atomic_load(&flags[idx], __ATOMIC_ACQUIRE,
                                        __HIP_MEMORY_SCOPE_AGENT);
                if (f != 0u) break;
                __builtin_amdgcn_s_sleep(2);
                ++spins;
            }
            // one acquire to order the payload reads (proven R5 semantics)
            (void)__hip_atomic_load(&flags[idx], __ATOMIC_ACQUIRE,
                                    __HIP_MEMORY_SCOPE_AGENT);
            const float* pp = agg + (size_t)idx * 12;
            Aff al, ah;
            al.a00 = __hip_atomic_load(pp + 0,  __ATOMIC_RELAXED, __HIP_MEMORY_SCOPE_AGENT);
            al.a01 = __hip_atomic_load(pp + 1,  __ATOMIC_RELAXED, __HIP_MEMORY_SCOPE_AGENT);
            al.a10 = __hip_atomic_load(pp + 2,  __ATOMIC_RELAXED, __HIP_MEMORY_SCOPE_AGENT);
            al.a11 = __hip_atomic_load(pp + 3,  __ATOMIC_RELAXED, __HIP_MEMORY_SCOPE_AGENT);
            al.c0  = __hip_atomic_load(pp + 4,  __ATOMIC_RELAXED, __HIP_MEMORY_SCOPE_AGENT);
            al.c1  = __hip_atomic_load(pp + 5,  __ATOMIC_RELAXED, __HIP_MEMORY_SCOPE_AGENT);
            ah.a00 = __hip_atomic_load(pp + 6,  __ATOMIC_RELAXED, __HIP_MEMORY_SCOPE_AGENT);
            ah.a01 = __hip_atomic_load(pp + 7,  __ATOMIC_RELAXED, __HIP_MEMORY_SCOPE_AGENT);
            ah.a10 = __hip_atomic_load(pp + 8,  __ATOMIC_RELAXED, __HIP_MEMORY_SCOPE_AGENT);
            ah.a11 = __hip_atomic_load(pp + 9,  __ATOMIC_RELAXED, __HIP_MEMORY_SCOPE_AGENT);
            ah.c0  = __hip_atomic_load(pp + 10, __ATOMIC_RELAXED, __HIP_MEMORY_SCOPE_AGENT);
            ah.c1  = __hip_atomic_load(pp + 11, __ATOMIC_RELAXED, __HIP_MEMORY_SCOPE_AGENT);
            ldsLBl[t] = al; ldsLBh[t] = ah;
        }
        __syncthreads();
        if (t == 0) {
            Aff rl = ldsLBl[0], rh = ldsLBh[0];
            for (int l = 1; l < bx; ++l) {
                rl = aff_compose(ldsLBl[l], rl);
                rh = aff_compose(ldsLBh[l], rh);
            }
            ldsCB[0] = rl.c0; ldsCB[1] = rl.c1;   // entry state = prefix(0)
            ldsCB[2] = rh.c0; ldsCB[3] = rh.c1;
        }
        __syncthreads();
    } else if (t == 0) {
        ldsCB[0] = 0.f; ldsCB[1] = 0.f; ldsCB[2] = 0.f; ldsCB[3] = 0.f;
    }
    if (bx == 0) __syncthreads();

    const float cbl0 = ldsCB[0], cbl1 = ldsCB[1];
    const float cbh0 = ldsCB[2], cbh1 = ldsCB[3];

    // exact init state for this thread's chunk: ex(cb)
    float yl1 = fmaf(exL.a00, cbl0, fmaf(exL.a01, cbl1, exL.c0));
    float yl2 = fmaf(exL.a10, cbl0, fmaf(exL.a11, cbl1, exL.c1));
    float yh1 = fmaf(exH.a00, cbh0, fmaf(exH.a01, cbh1, exH.c0));
    float yh2 = fmaf(exH.a10, cbh0, fmaf(exH.a11, cbh1, exH.c1));

    // ---- phase C: exact run; y staged through LDS, linear 32-KB stores ---
    float* __restrict__ oc = out + (size_t)ch * T_LEN;

    auto storeG = [&](int g) {
        #pragma unroll
        for (int i = 0; i < 8; ++i) {
            int f4 = i * 256 + t;
            int c  = f4 >> 4;
            int j0 = (f4 & 15) * 4;
            int ga = regBase + g * GFLT + f4 * 4;
            if (ga < T_LEN) {
                const float* sld = &lds[c * LSTR + j0];
                *(float4*)(oc + ga) = make_float4(sld[0], sld[1], sld[2], sld[3]);
            }
        }
    };

    // G0 x was prefetched into r before the scan; tile last read pre-scan.
    wreg();
    __syncthreads();
    ldreg(1);                          // in flight under G0 compute+store
    if ((t >> 7) == 0) {
        float* __restrict__ L = &lds[(t & 127) * LSTR];
        #pragma unroll
        for (int j = 0; j < CHUNK; ++j)
            L[j] = proc_sample(L[j], x1, x2, lo, hi, yl1, yl2, yh1, yh2);
    }
    __syncthreads();
    storeG(0);
    __syncthreads();
    wreg();
    __syncthreads();
    if ((t >> 7) == 1) {
        float* __restrict__ L = &lds[(t & 127) * LSTR];
        #pragma unroll
        for (int j = 0; j < CHUNK; ++j)
            L[j] = proc_sample(L[j], x1, x2, lo, hi, yl1, yl2, yh1, yh2);
    }
    __syncthreads();
    storeG(1);
}

} // namespace

extern "C" void kernel_launch(void* const* d_in, const int* in_sizes, int n_in,
                              void* d_out, int out_size, void* d_ws, size_t ws_size,
                              hipStream_t stream) {
    const float* audio = (const float*)d_in[0];
    const int*   srp   = (const int*)d_in[1];
    const float* clp   = (const float*)d_in[2];
    const float* chp   = (const float*)d_in[3];
    float* out = (float*)d_out;

    // ws layout: [NBLK] u32 flags | pad to 4096 B | [NBLK][12] f32 aggregates
    unsigned int* flags = (unsigned int*)d_ws;
    float* agg = (float*)((char*)d_ws + 4096);
    // ws needed: 4096 + 896*48 B ~= 47 KB

    hipMemsetAsync(flags, 0, NBLK * sizeof(unsigned int), stream);

    dim3 grid(BX, NCH);   // 14 x 64 = 896 blocks; capacity 4/CU * 256 = 1024
    hipLaunchKernelGGL(k_bandpass, grid, dim3(256), 0, stream,
                       audio, srp, clp, chp, agg, flags, out);
}

// Round 5
// 159.868 us; speedup vs baseline: 3.7181x; 1.0744x over previous
//
#include <hip/hip_runtime.h>
#include <math.h>

// BandpassFilter: out = lowpass_biquad(x) - highpass_biquad(x), f32,
// shape (32,2,220500). Exact chunked-scan parallelization of the order-2 IIR.
//
// R7: kill the spill + reuse the resident G1 tile.
// R6 post-mortem: WRITE_SIZE +29.4 MB == 229,376 threads x 128 B == one
// spill round-trip of float4 r[8]; VGPR_Count pinned at 64 (= 8 waves/EU
// boundary) because __launch_bounds__(256,4) only sets a MINIMUM of 4
// waves/EU and LLVM's allocator chased 8, spilling the buffer that is live
// across the scan. Fix: amdgpu_waves_per_eu(4,4) pins the range -> 128-VGPR
// budget, no spill, occupancy still the 4 blocks/CU that co-residency needs.
// Schedule fix: after phase-A's G1 compute the LDS tile STILL HOLDS G1's x
// (scan/lookback only touch the small side arrays), and phase-C group order
// is free -> phase C runs G1 first from the resident tile (one whole stage
// round-trip eliminated); the only phase-C reload is G0, issued right after
// the aggregate publish so the loads fly under the lookback spin (short,
// post-scan live range; fits the 128-VGPR budget).

namespace {

constexpr int T_LEN  = 220500;
constexpr int NCH    = 64;                          // 32 batch * 2 channels
constexpr int CHUNK  = 64;                          // samples per chunk
constexpr int NCHUNK = (T_LEN + CHUNK - 1) / CHUNK; // 3446 (last chunk = 20)
constexpr int CPB    = 256;                         // chunks per block
constexpr int BX     = (NCHUNK + CPB - 1) / CPB;    // 14 blocks along chunk dim
constexpr int NBLK   = BX * NCH;                    // 896 blocks
constexpr int GCH    = 128;                         // chunks per group (2 groups)
constexpr int GFLT   = GCH * CHUNK;                 // 8192 floats = 32 KB/group
constexpr int LSTR   = CHUNK + 1;                   // 65: pad-1, <=2-way banks

struct Coeffs { float b0, b1, b2, a1, a2; };

__device__ inline Coeffs make_coeffs(float sr, float cutoff, bool hp) {
    float w0 = 6.2831853071795864f * cutoff / sr;
    float c = cosf(w0), s = sinf(w0);
    float alpha = s / (2.0f * 0.707f);
    float b0, b1;
    if (!hp) { b0 = (1.0f - c) * 0.5f; b1 = 1.0f - c; }
    else     { b0 = (1.0f + c) * 0.5f; b1 = -(1.0f + c); }
    float inv = 1.0f / (1.0f + alpha);
    Coeffs k;
    k.b0 = b0 * inv; k.b1 = b1 * inv; k.b2 = b0 * inv;
    k.a1 = (-2.0f * c) * inv;
    k.a2 = (1.0f - alpha) * inv;
    return k;
}

// one sample through both filters; returns yl - yh
__device__ inline float proc_sample(float xn, float& x1, float& x2,
                                    const Coeffs& lo, const Coeffs& hi,
                                    float& yl1, float& yl2,
                                    float& yh1, float& yh2) {
    float ffl = fmaf(lo.b0, xn, fmaf(lo.b1, x1, lo.b2 * x2));
    float tl  = fmaf(-lo.a2, yl2, ffl);
    float yl  = fmaf(-lo.a1, yl1, tl);
    float ffh = fmaf(hi.b0, xn, fmaf(hi.b1, x1, hi.b2 * x2));
    float th  = fmaf(-hi.a2, yh2, ffh);
    float yh  = fmaf(-hi.a1, yh1, th);
    yl2 = yl1; yl1 = yl;
    yh2 = yh1; yh1 = yh;
    x2 = x1; x1 = xn;
    return yl - yh;
}

// Affine map s' = A*s + c on the 2-tap IIR state s = (y[n-1], y[n-2]).
struct Aff { float a00, a01, a10, a11, c0, c1; };

__device__ inline Aff aff_id() { return {1.f, 0.f, 0.f, 1.f, 0.f, 0.f}; }

// g o f : f applied first. Same formulas as the R2/R5-verified scan.
__device__ inline Aff aff_compose(const Aff& g, const Aff& f) {
    Aff r;
    r.a00 = fmaf(g.a00, f.a00, g.a01 * f.a10);
    r.a01 = fmaf(g.a00, f.a01, g.a01 * f.a11);
    r.a10 = fmaf(g.a10, f.a00, g.a11 * f.a10);
    r.a11 = fmaf(g.a10, f.a01, g.a11 * f.a11);
    r.c0  = fmaf(g.a00, f.c0, fmaf(g.a01, f.c1, g.c0));
    r.c1  = fmaf(g.a10, f.c0, fmaf(g.a11, f.c1, g.c1));
    return r;
}

__device__ inline Aff aff_shfl_up(const Aff& e, int d) {
    Aff p;
    p.a00 = __shfl_up(e.a00, d);
    p.a01 = __shfl_up(e.a01, d);
    p.a10 = __shfl_up(e.a10, d);
    p.a11 = __shfl_up(e.a11, d);
    p.c0  = __shfl_up(e.c0, d);
    p.c1  = __shfl_up(e.c1, d);
    return p;
}

// M^CHUNK for one filter: chunk transition matrix, CHUNK=64 via 6 squarings.
__device__ inline void chunk_matrix(const Coeffs& k,
                                    float& m00, float& m01,
                                    float& m10, float& m11) {
    m00 = -k.a1; m01 = -k.a2; m10 = 1.0f; m11 = 0.0f;
    #pragma unroll
    for (int i = 0; i < 6; ++i) {
        float t00 = fmaf(m00, m00, m01 * m10);
        float t01 = fmaf(m00, m01, m01 * m11);
        float t10 = fmaf(m10, m00, m11 * m10);
        float t11 = fmaf(m10, m01, m11 * m11);
        m00 = t00; m01 = t01; m10 = t10; m11 = t11;
    }
}

__global__ __launch_bounds__(256)
__attribute__((amdgpu_waves_per_eu(4, 4)))   // pin 4 waves/EU -> 128-VGPR
void k_bandpass(const float* __restrict__ x,  // budget, NO spill (R6 lesson)
                const int* __restrict__ srp,
                const float* __restrict__ clp,
                const float* __restrict__ chp,
                float* __restrict__ agg,          // [NBLK][12] published aggregates
                unsigned int* __restrict__ flags, // [NBLK] 0=empty 1=ready
                float* __restrict__ out) {
    __shared__ float lds[GCH * LSTR];          // 33,280 B group tile
    __shared__ Aff ldsWaveL[4], ldsWaveH[4];   // wave inclusive totals
    __shared__ Aff ldsWL[4],  ldsWH[4];        // wave exclusive prefixes
    __shared__ Aff ldsLBl[BX], ldsLBh[BX];     // lookback payloads
    __shared__ float ldsCB[4];                 // block entry state (lo, hi)

    const int t   = threadIdx.x;
    const int ch  = blockIdx.y;
    const int bx  = blockIdx.x;
    const int pb  = bx * CPB;
    const int p   = pb + t;
    const int bid = ch * BX + bx;

    float sr = (float)(*srp);
    Coeffs lo = make_coeffs(sr, *clp, false);
    Coeffs hi = make_coeffs(sr, *chp, true);

    const float* __restrict__ xc = x + (size_t)ch * T_LEN;
    const bool active = (p < NCHUNK);
    const int s = p * CHUNK;
    const int regBase = pb * CHUNK;

    // x history (exact; crosses chunk/block boundaries by direct global read)
    float x1 = (active && s >= 1) ? xc[s - 1] : 0.0f;
    float x2 = (active && s >= 2) ? xc[s - 2] : 0.0f;

    // ---- contiguous group staging primitives -----------------------------
    // group g = local chunks [g*128, g*128+128) = floats [g*GFLT, +GFLT):
    // fully linear 32-KB global bursts; OOB zero-filled (exactness: only the
    // last chunk's unused tail / never-stored region is padded).
    float4 r[8];   // reg buffer; all indexing compile-time constant

    auto ldreg = [&](int g) {
        #pragma unroll
        for (int i = 0; i < 8; ++i) {
            int f4 = i * 256 + t;
            int ga = regBase + g * GFLT + f4 * 4;
            if (ga < T_LEN) r[i] = *(const float4*)(xc + ga);  // T_LEN%4==0
            else            r[i] = make_float4(0.f, 0.f, 0.f, 0.f);
        }
    };
    auto wreg = [&]() {
        #pragma unroll
        for (int i = 0; i < 8; ++i) {
            int f4 = i * 256 + t;
            int c  = f4 >> 4;          // local chunk row 0..127
            int j0 = (f4 & 15) * 4;    // sample offset in chunk
            float* d = &lds[c * LSTR + j0];
            d[0] = r[i].x; d[1] = r[i].y; d[2] = r[i].z; d[3] = r[i].w;
        }
    };

    // ---- phase A: zero-state run, tails kept in registers ---------------
    float tl1 = 0.f, tl2 = 0.f, th1 = 0.f, th2 = 0.f;
    float ax1 = x1, ax2 = x2;

    ldreg(0);
    wreg();
    __syncthreads();
    ldreg(1);                          // in flight under G0 compute
    if ((t >> 7) == 0) {
        const float* __restrict__ L = &lds[(t & 127) * LSTR];
        #pragma unroll
        for (int j = 0; j < CHUNK; ++j)
            (void)proc_sample(L[j], ax1, ax2, lo, hi, tl1, tl2, th1, th2);
    }
    __syncthreads();
    wreg();
    __syncthreads();
    if ((t >> 7) == 1) {
        const float* __restrict__ L = &lds[(t & 127) * LSTR];
        #pragma unroll
        for (int j = 0; j < CHUNK; ++j)
            (void)proc_sample(L[j], ax1, ax2, lo, hi, tl1, tl2, th1, th2);
    }
    // tile holds G1's x from here through the scan (side arrays are separate)

    // ---- block-level affine scan over the 256 per-chunk maps ------------
    float Ml00, Ml01, Ml10, Ml11, Mh00, Mh01, Mh10, Mh11;
    chunk_matrix(lo, Ml00, Ml01, Ml10, Ml11);
    chunk_matrix(hi, Mh00, Mh01, Mh10, Mh11);

    Aff il = active ? Aff{Ml00, Ml01, Ml10, Ml11, tl1, tl2} : aff_id();
    Aff ih = active ? Aff{Mh00, Mh01, Mh10, Mh11, th1, th2} : aff_id();

    const int lane = t & 63;
    const int w    = t >> 6;

    #pragma unroll
    for (int d = 1; d < 64; d <<= 1) {
        Aff plx = aff_shfl_up(il, d);
        Aff phx = aff_shfl_up(ih, d);
        if (lane >= d) {
            il = aff_compose(il, plx);
            ih = aff_compose(ih, phx);
        }
    }
    if (lane == 63) { ldsWaveL[w] = il; ldsWaveH[w] = ih; }
    __syncthreads();

    if (t == 0) {
        Aff rl = aff_id(), rh = aff_id();
        #pragma unroll
        for (int ww = 0; ww < 4; ++ww) {
            ldsWL[ww] = rl; ldsWH[ww] = rh;
            rl = aff_compose(ldsWaveL[ww], rl);
            rh = aff_compose(ldsWaveH[ww], rh);
        }
        // publish block aggregate (proven R5 protocol: relaxed payload +
        // release flag, agent scope)
        float* pl = agg + (size_t)bid * 12;
        __hip_atomic_store(pl + 0,  rl.a00, __ATOMIC_RELAXED, __HIP_MEMORY_SCOPE_AGENT);
        __hip_atomic_store(pl + 1,  rl.a01, __ATOMIC_RELAXED, __HIP_MEMORY_SCOPE_AGENT);
        __hip_atomic_store(pl + 2,  rl.a10, __ATOMIC_RELAXED, __HIP_MEMORY_SCOPE_AGENT);
        __hip_atomic_store(pl + 3,  rl.a11, __ATOMIC_RELAXED, __HIP_MEMORY_SCOPE_AGENT);
        __hip_atomic_store(pl + 4,  rl.c0,  __ATOMIC_RELAXED, __HIP_MEMORY_SCOPE_AGENT);
        __hip_atomic_store(pl + 5,  rl.c1,  __ATOMIC_RELAXED, __HIP_MEMORY_SCOPE_AGENT);
        __hip_atomic_store(pl + 6,  rh.a00, __ATOMIC_RELAXED, __HIP_MEMORY_SCOPE_AGENT);
        __hip_atomic_store(pl + 7,  rh.a01, __ATOMIC_RELAXED, __HIP_MEMORY_SCOPE_AGENT);
        __hip_atomic_store(pl + 8,  rh.a10, __ATOMIC_RELAXED, __HIP_MEMORY_SCOPE_AGENT);
        __hip_atomic_store(pl + 9,  rh.a11, __ATOMIC_RELAXED, __HIP_MEMORY_SCOPE_AGENT);
        __hip_atomic_store(pl + 10, rh.c0,  __ATOMIC_RELAXED, __HIP_MEMORY_SCOPE_AGENT);
        __hip_atomic_store(pl + 11, rh.c1,  __ATOMIC_RELAXED, __HIP_MEMORY_SCOPE_AGENT);
        __hip_atomic_store(&flags[bid], 1u, __ATOMIC_RELEASE, __HIP_MEMORY_SCOPE_AGENT);
    }
    __syncthreads();

    // per-thread block-exclusive prefix = (wave-exclusive of thread) o W[wave]
    Aff exL, exH;
    {
        Aff pl_ = aff_shfl_up(il, 1);
        Aff ph_ = aff_shfl_up(ih, 1);
        if (lane == 0) { pl_ = aff_id(); ph_ = aff_id(); }
        exL = aff_compose(pl_, ldsWL[w]);
        exH = aff_compose(ph_, ldsWH[w]);
    }

    // phase-C G0 reload issued NOW: loads fly under the lookback spin;
    // live range is short (post-scan) and fits the pinned 128-VGPR budget.
    ldreg(0);

    // ---- lookback: wave 0 polls the <=13 predecessors of this channel ----
    if (bx > 0) {
        if (t < bx) {   // lanes 0..bx-1 of wave 0
            int idx = ch * BX + t;
            // cache-neutral spin (proven R6): relaxed SYSTEM loads; hang-
            // proof fallback to the proven acquire-AGENT load after 1024.
            int spins = 0;
            for (;;) {
                unsigned int f = (spins < 1024)
                    ? __hip_atomic_load(&flags[idx], __ATOMIC_RELAXED,
                                        __HIP_MEMORY_SCOPE_SYSTEM)
                    : __hip_atomic_load(&flags[idx], __ATOMIC_ACQUIRE,
                                        __HIP_MEMORY_SCOPE_AGENT);
                if (f != 0u) break;
                __builtin_amdgcn_s_sleep(2);
                ++spins;
            }
            // one acquire to order the payload reads (proven R5 semantics)
            (void)__hip_atomic_load(&flags[idx], __ATOMIC_ACQUIRE,
                                    __HIP_MEMORY_SCOPE_AGENT);
            const float* pp = agg + (size_t)idx * 12;
            Aff al, ah;
            al.a00 = __hip_atomic_load(pp + 0,  __ATOMIC_RELAXED, __HIP_MEMORY_SCOPE_AGENT);
            al.a01 = __hip_atomic_load(pp + 1,  __ATOMIC_RELAXED, __HIP_MEMORY_SCOPE_AGENT);
            al.a10 = __hip_atomic_load(pp + 2,  __ATOMIC_RELAXED, __HIP_MEMORY_SCOPE_AGENT);
            al.a11 = __hip_atomic_load(pp + 3,  __ATOMIC_RELAXED, __HIP_MEMORY_SCOPE_AGENT);
            al.c0  = __hip_atomic_load(pp + 4,  __ATOMIC_RELAXED, __HIP_MEMORY_SCOPE_AGENT);
            al.c1  = __hip_atomic_load(pp + 5,  __ATOMIC_RELAXED, __HIP_MEMORY_SCOPE_AGENT);
            ah.a00 = __hip_atomic_load(pp + 6,  __ATOMIC_RELAXED, __HIP_MEMORY_SCOPE_AGENT);
            ah.a01 = __hip_atomic_load(pp + 7,  __ATOMIC_RELAXED, __HIP_MEMORY_SCOPE_AGENT);
            ah.a10 = __hip_atomic_load(pp + 8,  __ATOMIC_RELAXED, __HIP_MEMORY_SCOPE_AGENT);
            ah.a11 = __hip_atomic_load(pp + 9,  __ATOMIC_RELAXED, __HIP_MEMORY_SCOPE_AGENT);
            ah.c0  = __hip_atomic_load(pp + 10, __ATOMIC_RELAXED, __HIP_MEMORY_SCOPE_AGENT);
            ah.c1  = __hip_atomic_load(pp + 11, __ATOMIC_RELAXED, __HIP_MEMORY_SCOPE_AGENT);
            ldsLBl[t] = al; ldsLBh[t] = ah;
        }
        __syncthreads();
        if (t == 0) {
            Aff rl = ldsLBl[0], rh = ldsLBh[0];
            for (int l = 1; l < bx; ++l) {
                rl = aff_compose(ldsLBl[l], rl);
                rh = aff_compose(ldsLBh[l], rh);
            }
            ldsCB[0] = rl.c0; ldsCB[1] = rl.c1;   // entry state = prefix(0)
            ldsCB[2] = rh.c0; ldsCB[3] = rh.c1;
        }
        __syncthreads();
    } else if (t == 0) {
        ldsCB[0] = 0.f; ldsCB[1] = 0.f; ldsCB[2] = 0.f; ldsCB[3] = 0.f;
    }
    if (bx == 0) __syncthreads();

    const float cbl0 = ldsCB[0], cbl1 = ldsCB[1];
    const float cbh0 = ldsCB[2], cbh1 = ldsCB[3];

    // exact init state for this thread's chunk: ex(cb)
    float yl1 = fmaf(exL.a00, cbl0, fmaf(exL.a01, cbl1, exL.c0));
    float yl2 = fmaf(exL.a10, cbl0, fmaf(exL.a11, cbl1, exL.c1));
    float yh1 = fmaf(exH.a00, cbh0, fmaf(exH.a01, cbh1, exH.c0));
    float yh2 = fmaf(exH.a10, cbh0, fmaf(exH.a11, cbh1, exH.c1));

    // ---- phase C: G1 FIRST from the resident tile (no restage), then G0 --
    float* __restrict__ oc = out + (size_t)ch * T_LEN;

    auto storeG = [&](int g) {
        #pragma unroll
        for (int i = 0; i < 8; ++i) {
            int f4 = i * 256 + t;
            int c  = f4 >> 4;
            int j0 = (f4 & 15) * 4;
            int ga = regBase + g * GFLT + f4 * 4;
            if (ga < T_LEN) {
                const float* sld = &lds[c * LSTR + j0];
                *(float4*)(oc + ga) = make_float4(sld[0], sld[1], sld[2], sld[3]);
            }
        }
    };

    if ((t >> 7) == 1) {               // G1 owners: tile already holds G1 x
        float* __restrict__ L = &lds[(t & 127) * LSTR];
        #pragma unroll
        for (int j = 0; j < CHUNK; ++j)
            L[j] = proc_sample(L[j], x1, x2, lo, hi, yl1, yl2, yh1, yh2);
    }
    __syncthreads();
    storeG(1);
    __syncthreads();
    wreg();                            // G0 x (loaded under the lookback)
    __syncthreads();
    if ((t >> 7) == 0) {
        float* __restrict__ L = &lds[(t & 127) * LSTR];
        #pragma unroll
        for (int j = 0; j < CHUNK; ++j)
            L[j] = proc_sample(L[j], x1, x2, lo, hi, yl1, yl2, yh1, yh2);
    }
    __syncthreads();
    storeG(0);
}

} // namespace

extern "C" void kernel_launch(void* const* d_in, const int* in_sizes, int n_in,
                              void* d_out, int out_size, void* d_ws, size_t ws_size,
                              hipStream_t stream) {
    const float* audio = (const float*)d_in[0];
    const int*   srp   = (const int*)d_in[1];
    const float* clp   = (const float*)d_in[2];
    const float* chp   = (const float*)d_in[3];
    float* out = (float*)d_out;

    // ws layout: [NBLK] u32 flags | pad to 4096 B | [NBLK][12] f32 aggregates
    unsigned int* flags = (unsigned int*)d_ws;
    float* agg = (float*)((char*)d_ws + 4096);
    // ws needed: 4096 + 896*48 B ~= 47 KB

    hipMemsetAsync(flags, 0, NBLK * sizeof(unsigned int), stream);

    dim3 grid(BX, NCH);   // 14 x 64 = 896 blocks; capacity 4/CU * 256 = 1024
    hipLaunchKernelGGL(k_bandpass, grid, dim3(256), 0, stream,
                       audio, srp, clp, chp, agg, flags, out);
}